// Round 8
// baseline (210.858 us; speedup 1.0000x reference)
//
#include <hip/hip_runtime.h>
#include <hip/hip_bf16.h>

#define FH 240
#define FIT_IN 1600
#define NK 2048            // table knots per e
#define TLO -16.0f
#define TINVH 64.0f        // knots per unit S (h = 1/64)

typedef _Float16 h8 __attribute__((ext_vector_type(8)));
typedef float f4v __attribute__((ext_vector_type(4)));

__device__ __forceinline__ float fast_tanh(float x) {
    float e2 = __builtin_amdgcn_exp2f(x * 2.8853900817779268f);
    return 1.0f - 2.0f * __builtin_amdgcn_rcpf(e2 + 1.0f);
}

#define FMA_ROW(r, s) \
    acc[r][0] += (s) * b0.x; acc[r][1] += (s) * b0.y; \
    acc[r][2] += (s) * b0.z; acc[r][3] += (s) * b0.w; \
    acc[r][4] += (s) * b1.x; acc[r][5] += (s) * b1.y; \
    acc[r][6] += (s) * b1.z; acc[r][7] += (s) * b1.w;

// ---------------------------------------------------------------------------
// k_prep: blocks 0..63 build the embedding table (R6 GEMM structure);
// blocks 64..127 convert/transpose fit weights to f16.
// ---------------------------------------------------------------------------
#define TOFF_W0   0
#define TOFF_B0   28
#define TOFF_B1   56
#define TOFF_B2   108
#define TOFF_W1   208
#define TOFF_W2   1508
#define TOFF_H0T  6708
#define TOFF_H1T  10008
#define TSMEM     16608

__global__ __launch_bounds__(256) void k_prep(
    const float* __restrict__ eW0, const float* __restrict__ eB0,
    const float* __restrict__ eW1, const float* __restrict__ eB1,
    const float* __restrict__ eW2, const float* __restrict__ eB2,
    float* __restrict__ T,
    const float* __restrict__ fW0, const float* __restrict__ fW1,
    const float* __restrict__ fW2,
    _Float16* __restrict__ W0T, _Float16* __restrict__ W1T,
    _Float16* __restrict__ W2T)
{
    const int bx = blockIdx.x;
    const int t  = threadIdx.x;

    if (bx >= 64) {
        // ---- weight convert: coalesced reads, scattered f16 writes ----
        const int total = 768000 + 115200 + 115200;
        for (int idx = (bx - 64) * 256 + t; idx < total; idx += 64 * 256) {
            if (idx < 768000) {
                const int tp = idx / 384000, r = idx - tp * 384000;
                const int k = r / 240, n = r - k * 240;
                W0T[tp * 384000 + n * 1600 + k] = (_Float16)fW0[idx];
            } else if (idx < 883200) {
                const int j = idx - 768000;
                const int tp = j / 57600, r = j - tp * 57600;
                const int k = r / 240, n = r - k * 240;
                W1T[tp * 57600 + n * 240 + k] = (_Float16)fW1[j];
            } else {
                const int j = idx - 883200;
                const int tp = j / 57600, r = j - tp * 57600;
                const int k = r / 240, n = r - k * 240;
                W2T[tp * 57600 + n * 240 + k] = (_Float16)fW2[j];
            }
        }
        return;
    }

    __shared__ float sm[TSMEM];
    const int w    = t >> 6;
    const int lane = t & 63;
    const int mi   = lane & 7;
    const int gi   = lane >> 3;
    const int mrow = w * 32 + mi * 4;

    const int e  = bx >> 4;
    const int k0 = (bx & 15) * 128;

    for (int idx = t; idx < 1250; idx += 256) {
        int k = idx / 50, g = idx - k * 50;
        sm[TOFF_W1 + k * 52 + g] = eW1[e * 1250 + idx];
    }
    for (int idx = t; idx < 5000; idx += 256) {
        int k = idx / 100, r = idx - k * 100;
        int half = r / 50, g = r - half * 50;
        sm[TOFF_W2 + k * 104 + half * 52 + g] = eW2[e * 5000 + idx];
    }
    if (t < 25)       { sm[TOFF_W0 + t] = eW0[e * 25 + t]; sm[TOFF_B0 + t] = eB0[e * 25 + t]; }
    else if (t < 75)  { sm[TOFF_B1 + (t - 25)] = eB1[e * 50 + (t - 25)]; }
    else if (t < 175) { sm[TOFF_B2 + (t - 75)] = eB2[e * 100 + (t - 75)]; }
    __syncthreads();

    if (t < 128) {
        const float S = TLO + (float)(k0 + t) * (1.0f / TINVH);
        #pragma unroll
        for (int k = 0; k < 25; ++k)
            sm[TOFF_H0T + k * 132 + t] = fast_tanh(S * sm[TOFF_W0 + k] + sm[TOFF_B0 + k]);
    }
    __syncthreads();

    {
        float acc[4][8];
        #pragma unroll
        for (int r = 0; r < 4; ++r)
            #pragma unroll
            for (int c = 0; c < 8; ++c) acc[r][c] = 0.f;

        #pragma unroll 5
        for (int k = 0; k < 25; ++k) {
            const float4 av = *(const float4*)&sm[TOFF_H0T + k * 132 + mrow];
            const float4 b0 = *(const float4*)&sm[TOFF_W1 + k * 52 + gi * 8];
            const float4 b1 = *(const float4*)&sm[TOFF_W1 + k * 52 + gi * 8 + 4];
            FMA_ROW(0, av.x) FMA_ROW(1, av.y) FMA_ROW(2, av.z) FMA_ROW(3, av.w)
        }
        #pragma unroll
        for (int c = 0; c < 8; ++c) {
            const int g = gi * 8 + c;
            if (g < 50) {
                const int gm = (g < 25) ? g : g - 25;
                const float4 h0r = *(const float4*)&sm[TOFF_H0T + gm * 132 + mrow];
                const float bias = sm[TOFF_B1 + g];
                float4 o;
                o.x = fast_tanh(acc[0][c] + bias) + h0r.x;
                o.y = fast_tanh(acc[1][c] + bias) + h0r.y;
                o.z = fast_tanh(acc[2][c] + bias) + h0r.z;
                o.w = fast_tanh(acc[3][c] + bias) + h0r.w;
                *(float4*)&sm[TOFF_H1T + g * 132 + mrow] = o;
            }
        }
    }
    __syncthreads();

    for (int half = 0; half < 2; ++half) {
        float acc[4][8];
        #pragma unroll
        for (int r = 0; r < 4; ++r)
            #pragma unroll
            for (int c = 0; c < 8; ++c) acc[r][c] = 0.f;

        #pragma unroll 5
        for (int k = 0; k < 50; ++k) {
            const float4 av = *(const float4*)&sm[TOFF_H1T + k * 132 + mrow];
            const float4 b0 = *(const float4*)&sm[TOFF_W2 + k * 104 + half * 52 + gi * 8];
            const float4 b1 = *(const float4*)&sm[TOFF_W2 + k * 104 + half * 52 + gi * 8 + 4];
            FMA_ROW(0, av.x) FMA_ROW(1, av.y) FMA_ROW(2, av.z) FMA_ROW(3, av.w)
        }
        #pragma unroll
        for (int c = 0; c < 8; ++c) {
            const int g = gi * 8 + c;
            if (g < 50) {
                const float4 h1r = *(const float4*)&sm[TOFF_H1T + g * 132 + mrow];
                const float bias = sm[TOFF_B2 + half * 50 + g];
                float* out = T + ((size_t)e * NK + k0 + mrow) * 100 + half * 50 + g;
                out[0]   = fast_tanh(acc[0][c] + bias) + h1r.x;
                out[100] = fast_tanh(acc[1][c] + bias) + h1r.y;
                out[200] = fast_tanh(acc[2][c] + bias) + h1r.z;
                out[300] = fast_tanh(acc[3][c] + bias) + h1r.w;
            }
        }
    }
}

// ---------------------------------------------------------------------------
// k_xyz: per atom gather+lerp from table + reduce. All 4 waves split the
// m-loop (64 iters/wave); all 64 lanes carry g=lane, lanes<36 also g=64+lane.
// ---------------------------------------------------------------------------
__global__ __launch_bounds__(256) void k_xyz(
    const float* __restrict__ Ri, const float* __restrict__ T,
    _Float16* __restrict__ DRh)
{
    __shared__ float4 sR[256];
    __shared__ float  sF[256];
    __shared__ int    sI[256];
    __shared__ float  sXYZ[400];

    const int t    = threadIdx.x;
    const int w    = t >> 6;
    const int lane = t & 63;
    const int blk  = blockIdx.x;         // 0..2047
    const int b    = blk >> 9;
    const int i    = (blk >> 8) & 1;
    const int n    = blk & 255;

    for (int idx = t; idx < 400; idx += 256) sXYZ[idx] = 0.f;

    {
        const int jj = t >> 7, m = t & 127;
        const size_t row = ((size_t)(b * 512 + i * 256 + n)) * 256 + jj * 128 + m;
        const float4 r = *(const float4*)(Ri + row * 4);
        sR[t] = r;
        float u = (r.x - TLO) * TINVH;
        int ii = (int)u;
        ii = (ii < 0) ? 0 : ((ii > NK - 2) ? NK - 2 : ii);
        sI[t] = ii;
        sF[t] = u - (float)ii;
    }
    __syncthreads();

    float a0[4] = {0.f, 0.f, 0.f, 0.f};
    float a1[4] = {0.f, 0.f, 0.f, 0.f};

    for (int jj = 0; jj < 2; ++jj) {
        const float* Te = T + (size_t)(i * 2 + jj) * NK * 100;
        #pragma unroll 4
        for (int mm = 0; mm < 32; ++mm) {
            const int s = jj * 128 + (w << 5) + mm;
            const int row = sI[s];
            const float f = sF[s];
            const float4 R = sR[s];
            const float* p = Te + (size_t)row * 100;
            const float v0 = p[lane], v1 = p[100 + lane];
            const float G = v0 + f * (v1 - v0);
            a0[0] += R.x * G; a0[1] += R.y * G; a0[2] += R.z * G; a0[3] += R.w * G;
            if (lane < 36) {
                const float u0 = p[64 + lane], u1 = p[164 + lane];
                const float G2 = u0 + f * (u1 - u0);
                a1[0] += R.x * G2; a1[1] += R.y * G2; a1[2] += R.z * G2; a1[3] += R.w * G2;
            }
        }
    }

    #pragma unroll
    for (int c = 0; c < 4; ++c) atomicAdd(&sXYZ[c * 100 + lane], a0[c]);
    if (lane < 36) {
        #pragma unroll
        for (int c = 0; c < 4; ++c) atomicAdd(&sXYZ[c * 100 + 64 + lane], a1[c]);
    }
    __syncthreads();

    const float inv = 1.0f / 65536.0f;
    _Float16* dr = DRh + (((size_t)i * 4 + b) * 256 + n) * FIT_IN;
    for (int q = t; q < 400; q += 256) {
        const int gg = q >> 2, h0 = (q & 3) * 4;
        ushort4 pk;
        _Float16* ph = (_Float16*)&pk;
        #pragma unroll
        for (int r = 0; r < 4; ++r) {
            const int h = h0 + r;
            const float v = (sXYZ[gg] * sXYZ[h] + sXYZ[100 + gg] * sXYZ[100 + h]
                           + sXYZ[200 + gg] * sXYZ[200 + h] + sXYZ[300 + gg] * sXYZ[300 + h]) * inv;
            ph[r] = (_Float16)v;
        }
        *(ushort4*)(dr + gg * 16 + h0) = pk;
    }
}

// ---------------------------------------------------------------------------
// k_fit0: split-K partial GEMM for layer 0. M=32 tile, N=240, f16 MFMA.
// grid (64 m-tiles, 8 k-slices). P[ks][2048][240] f32.
// ---------------------------------------------------------------------------
__global__ __launch_bounds__(256) void k_fit0(
    const _Float16* __restrict__ A, const _Float16* __restrict__ WT,
    float* __restrict__ P)
{
    constexpr int K = FIT_IN, CHUNK = 200;
    __shared__ _Float16 sA[32 * 40];
    __shared__ _Float16 sBT[240 * 40];

    const int t    = threadIdx.x;
    const int w    = t >> 6;
    const int lane = t & 63;
    const int ln   = lane & 15;
    const int quad = lane >> 4;

    const int mtile = blockIdx.x;        // 0..63
    const int ks    = blockIdx.y;        // 0..7
    const int row0  = mtile * 32;
    const int tp    = mtile >> 5;
    const int kbeg  = ks * CHUNK, kend = kbeg + CHUNK;
    const int nf0   = w * 4;

    f4v acc[2][4];
    #pragma unroll
    for (int mf = 0; mf < 2; ++mf)
        #pragma unroll
        for (int nf = 0; nf < 4; ++nf) acc[mf][nf] = (f4v)0.f;

    const _Float16* Ab = A + (size_t)row0 * K;
    const _Float16* Wb = WT + (size_t)tp * 240 * K;

    for (int k0 = kbeg; k0 < kend; k0 += 32) {
        {
            const int m = t >> 3, kq = (t & 7) * 4;
            const int k = k0 + kq;
            uint2 v = make_uint2(0u, 0u);
            if (k < kend) v = *(const uint2*)(Ab + (size_t)m * K + k);
            *(uint2*)&sA[m * 40 + kq] = v;
        }
        for (int q = t; q < 1920; q += 256) {
            const int nn = q >> 3, kq = (q & 7) * 4;
            const int k = k0 + kq;
            uint2 v = make_uint2(0u, 0u);
            if (k < kend) v = *(const uint2*)(Wb + (size_t)nn * K + k);
            *(uint2*)&sBT[nn * 40 + kq] = v;
        }
        __syncthreads();

        h8 afr[2];
        #pragma unroll
        for (int mf = 0; mf < 2; ++mf)
            afr[mf] = *(const h8*)&sA[(mf * 16 + ln) * 40 + quad * 8];
        #pragma unroll
        for (int nf = 0; nf < 4; ++nf) {
            const int n15 = nf0 + nf;
            if (n15 < 15) {
                const h8 bfr = *(const h8*)&sBT[(n15 * 16 + ln) * 40 + quad * 8];
                #pragma unroll
                for (int mf = 0; mf < 2; ++mf)
                    acc[mf][nf] = __builtin_amdgcn_mfma_f32_16x16x32_f16(
                        afr[mf], bfr, acc[mf][nf], 0, 0, 0);
            }
        }
        __syncthreads();
    }

    float* Pb = P + ((size_t)ks * 2048 + row0) * FH;
    #pragma unroll
    for (int nf = 0; nf < 4; ++nf) {
        const int n15 = nf0 + nf;
        if (n15 < 15) {
            const int col = n15 * 16 + ln;
            #pragma unroll
            for (int mf = 0; mf < 2; ++mf)
                #pragma unroll
                for (int r = 0; r < 4; ++r)
                    Pb[(size_t)(mf * 16 + quad * 4 + r) * FH + col] = acc[mf][nf][r];
        }
    }
}

// ---------------------------------------------------------------------------
// k_fit_reduce: v = tanh(sum_ks P + bias); writes f32 + f16.
// ---------------------------------------------------------------------------
__global__ __launch_bounds__(256) void k_fit_reduce(
    const float* __restrict__ P, const float* __restrict__ Bias,
    float* __restrict__ OutF, _Float16* __restrict__ OutH)
{
    const int idx = blockIdx.x * 256 + threadIdx.x;
    if (idx >= 2048 * FH) return;
    const int tp  = idx / (1024 * FH);
    const int col = idx % FH;
    float s = 0.f;
    #pragma unroll
    for (int ks = 0; ks < 8; ++ks)
        s += P[(size_t)ks * 2048 * FH + idx];
    const float v = fast_tanh(s + Bias[tp * FH + col]);
    OutF[idx] = v;
    OutH[idx] = (_Float16)v;
}

// ---------------------------------------------------------------------------
// k_fit_layer: fused single-pass layer (K=240): Out = tanh(A@W+b) + Res.
// M=16 rows x N=240 per block, grid 128. Writes f32 + f16.
// ---------------------------------------------------------------------------
__global__ __launch_bounds__(256) void k_fit_layer(
    const _Float16* __restrict__ Ah, const _Float16* __restrict__ WT,
    const float* __restrict__ Bias, const float* __restrict__ ResF,
    float* __restrict__ OutF, _Float16* __restrict__ OutH)
{
    __shared__ _Float16 sA[16 * 264];    // [m][k] full K, stride 264
    __shared__ _Float16 sBT[240 * 40];

    const int t    = threadIdx.x;
    const int w    = t >> 6;
    const int lane = t & 63;
    const int ln   = lane & 15;
    const int quad = lane >> 4;

    const int m0 = blockIdx.x * 16;
    const int tp = m0 >> 10;
    const int nf0 = w * 4;

    // stage full A tile 16x240 (zero-pad k 240..263)
    for (int q = t; q < 1056; q += 256) {
        const int m = q / 66, kq = (q - m * 66) * 4;
        uint2 v = make_uint2(0u, 0u);
        if (kq < 240) v = *(const uint2*)(Ah + (size_t)(m0 + m) * 240 + kq);
        *(uint2*)&sA[m * 264 + kq] = v;
    }

    const _Float16* Wb = WT + (size_t)tp * 240 * 240;

    f4v acc[4];
    #pragma unroll
    for (int nf = 0; nf < 4; ++nf) acc[nf] = (f4v)0.f;

    for (int k0 = 0; k0 < 240; k0 += 32) {
        for (int q = t; q < 1920; q += 256) {
            const int nn = q >> 3, kq = (q & 7) * 4;
            const int k = k0 + kq;
            uint2 v = make_uint2(0u, 0u);
            if (k < 240) v = *(const uint2*)(Wb + (size_t)nn * 240 + k);
            *(uint2*)&sBT[nn * 40 + kq] = v;
        }
        __syncthreads();

        const h8 afr = *(const h8*)&sA[ln * 264 + k0 + quad * 8];
        #pragma unroll
        for (int nf = 0; nf < 4; ++nf) {
            const int n15 = nf0 + nf;
            if (n15 < 15) {
                const h8 bfr = *(const h8*)&sBT[(n15 * 16 + ln) * 40 + quad * 8];
                acc[nf] = __builtin_amdgcn_mfma_f32_16x16x32_f16(afr, bfr, acc[nf], 0, 0, 0);
            }
        }
        __syncthreads();
    }

    #pragma unroll
    for (int nf = 0; nf < 4; ++nf) {
        const int n15 = nf0 + nf;
        if (n15 < 15) {
            const int col = n15 * 16 + ln;
            #pragma unroll
            for (int r = 0; r < 4; ++r) {
                const int row = quad * 4 + r;
                const size_t o = (size_t)(m0 + row) * FH + col;
                const float v = fast_tanh(acc[nf][r] + Bias[tp * FH + col]) + ResF[o];
                OutF[o] = v;
                OutH[o] = (_Float16)v;
            }
        }
    }
}

// ---------------------------------------------------------------------------
// k_fit_last: layer 2 fused with the final W3 dot product.
// ---------------------------------------------------------------------------
__global__ __launch_bounds__(256) void k_fit_last(
    const _Float16* __restrict__ Ah, const _Float16* __restrict__ WT,
    const float* __restrict__ Bias, const float* __restrict__ ResF,
    const float* __restrict__ W3, const float* __restrict__ b3,
    float* __restrict__ out)
{
    __shared__ _Float16 sA[16 * 264];
    __shared__ _Float16 sBT[240 * 40];
    __shared__ float sH[16 * 244];
    __shared__ float sW3[240];

    const int t    = threadIdx.x;
    const int w    = t >> 6;
    const int lane = t & 63;
    const int ln   = lane & 15;
    const int quad = lane >> 4;

    const int m0 = blockIdx.x * 16;
    const int tp = m0 >> 10;
    const int nf0 = w * 4;

    for (int q = t; q < 1056; q += 256) {
        const int m = q / 66, kq = (q - m * 66) * 4;
        uint2 v = make_uint2(0u, 0u);
        if (kq < 240) v = *(const uint2*)(Ah + (size_t)(m0 + m) * 240 + kq);
        *(uint2*)&sA[m * 264 + kq] = v;
    }
    if (t < 240) sW3[t] = W3[tp * 240 + t];

    const _Float16* Wb = WT + (size_t)tp * 240 * 240;

    f4v acc[4];
    #pragma unroll
    for (int nf = 0; nf < 4; ++nf) acc[nf] = (f4v)0.f;

    for (int k0 = 0; k0 < 240; k0 += 32) {
        for (int q = t; q < 1920; q += 256) {
            const int nn = q >> 3, kq = (q & 7) * 4;
            const int k = k0 + kq;
            uint2 v = make_uint2(0u, 0u);
            if (k < 240) v = *(const uint2*)(Wb + (size_t)nn * 240 + k);
            *(uint2*)&sBT[nn * 40 + kq] = v;
        }
        __syncthreads();

        const h8 afr = *(const h8*)&sA[ln * 264 + k0 + quad * 8];
        #pragma unroll
        for (int nf = 0; nf < 4; ++nf) {
            const int n15 = nf0 + nf;
            if (n15 < 15) {
                const h8 bfr = *(const h8*)&sBT[(n15 * 16 + ln) * 40 + quad * 8];
                acc[nf] = __builtin_amdgcn_mfma_f32_16x16x32_f16(afr, bfr, acc[nf], 0, 0, 0);
            }
        }
        __syncthreads();
    }

    #pragma unroll
    for (int nf = 0; nf < 4; ++nf) {
        const int n15 = nf0 + nf;
        if (n15 < 15) {
            const int col = n15 * 16 + ln;
            #pragma unroll
            for (int r = 0; r < 4; ++r) {
                const int row = quad * 4 + r;
                sH[row * 244 + col] = fast_tanh(acc[nf][r] + Bias[tp * FH + col])
                                    + ResF[(size_t)(m0 + row) * FH + col];
            }
        }
    }
    __syncthreads();

    // final dot: wave w handles rows w*4 .. w*4+3
    #pragma unroll
    for (int rr = 0; rr < 4; ++rr) {
        const int row = w * 4 + rr;
        float s = 0.f;
        for (int c = lane; c < 240; c += 64) s += sH[row * 244 + c] * sW3[c];
        #pragma unroll
        for (int off = 32; off > 0; off >>= 1) s += __shfl_down(s, off);
        if (lane == 0) {
            const int g = m0 + row;          // 0..2047 = tp*1024 + b*256 + n
            const int rem = g & 1023;
            const int bb = rem >> 8, nn = rem & 255;
            out[bb * 512 + tp * 256 + nn] = s + b3[tp];
        }
    }
}

// ---------------------------------------------------------------------------
extern "C" void kernel_launch(void* const* d_in, const int* in_sizes, int n_in,
                              void* d_out, int out_size, void* d_ws, size_t ws_size,
                              hipStream_t stream)
{
    const float* Ri  = (const float*)d_in[0];
    const float* eW0 = (const float*)d_in[1];
    const float* eB0 = (const float*)d_in[2];
    const float* eW1 = (const float*)d_in[3];
    const float* eB1 = (const float*)d_in[4];
    const float* eW2 = (const float*)d_in[5];
    const float* eB2 = (const float*)d_in[6];
    const float* fW0 = (const float*)d_in[7];
    const float* fb0 = (const float*)d_in[8];
    const float* fW1 = (const float*)d_in[9];
    const float* fb1 = (const float*)d_in[10];
    const float* fW2 = (const float*)d_in[11];
    const float* fb2 = (const float*)d_in[12];
    const float* fW3 = (const float*)d_in[13];
    const float* fb3 = (const float*)d_in[14];

    char* p = (char*)d_ws;
    float* T      = (float*)p;      p += (size_t)4 * NK * 100 * 4;     // 3.28 MB
    float* P      = (float*)p;      p += (size_t)8 * 2048 * FH * 4;    // 15.7 MB
    float* hA     = (float*)p;      p += (size_t)2048 * FH * 4;
    float* hB     = (float*)p;      p += (size_t)2048 * FH * 4;
    _Float16* DRh = (_Float16*)p;   p += (size_t)2048 * FIT_IN * 2;
    _Float16* hAh = (_Float16*)p;   p += (size_t)2048 * FH * 2;
    _Float16* hBh = (_Float16*)p;   p += (size_t)2048 * FH * 2;
    _Float16* W0T = (_Float16*)p;   p += (size_t)768000 * 2;
    _Float16* W1T = (_Float16*)p;   p += (size_t)115200 * 2;
    _Float16* W2T = (_Float16*)p;   p += (size_t)115200 * 2;

    const int RBLK = (2048 * FH + 255) / 256;

    k_prep<<<dim3(128), dim3(256), 0, stream>>>(eW0, eB0, eW1, eB1, eW2, eB2, T,
                                                fW0, fW1, fW2, W0T, W1T, W2T);
    k_xyz<<<dim3(2048), dim3(256), 0, stream>>>(Ri, T, DRh);

    k_fit0<<<dim3(64, 8), dim3(256), 0, stream>>>(DRh, W0T, P);
    k_fit_reduce<<<dim3(RBLK), dim3(256), 0, stream>>>(P, fb0, hA, hAh);

    k_fit_layer<<<dim3(128), dim3(256), 0, stream>>>(hAh, W1T, fb1, hA, hB, hBh);
    k_fit_last<<<dim3(128), dim3(256), 0, stream>>>(hBh, W2T, fb2, hB, fW3, fb3,
                                                    (float*)d_out);
}

// Round 10
// 208.296 us; speedup vs baseline: 1.0123x; 1.0123x over previous
//
#include <hip/hip_runtime.h>
#include <hip/hip_bf16.h>

#define FH 240
#define FIT_IN 1600
#define NK 2048            // table knots per e
#define TLO -16.0f
#define TINVH 64.0f        // knots per unit S (h = 1/64)

typedef _Float16 h8 __attribute__((ext_vector_type(8)));
typedef _Float16 h2v __attribute__((ext_vector_type(2)));
typedef float f4v __attribute__((ext_vector_type(4)));

__device__ __forceinline__ float fast_tanh(float x) {
    float e2 = __builtin_amdgcn_exp2f(x * 2.8853900817779268f);
    return 1.0f - 2.0f * __builtin_amdgcn_rcpf(e2 + 1.0f);
}

#define FMA_ROW(r, s) \
    acc[r][0] += (s) * b0.x; acc[r][1] += (s) * b0.y; \
    acc[r][2] += (s) * b0.z; acc[r][3] += (s) * b0.w; \
    acc[r][4] += (s) * b1.x; acc[r][5] += (s) * b1.y; \
    acc[r][6] += (s) * b1.z; acc[r][7] += (s) * b1.w;

// ---------------------------------------------------------------------------
// k_prep: blocks 0..63 build the f16-PAIR embedding table
// Tp[e][knot][g] = (v[knot], v[knot+1]); blocks 64..127 convert fit weights.
// ---------------------------------------------------------------------------
#define TOFF_W0   0
#define TOFF_B0   28
#define TOFF_B1   56
#define TOFF_B2   108
#define TOFF_W1   208
#define TOFF_W2   1508
#define TOFF_H0T  6708
#define TOFF_H1T  10008
#define TSMEM     16608

__global__ __launch_bounds__(256) void k_prep(
    const float* __restrict__ eW0, const float* __restrict__ eB0,
    const float* __restrict__ eW1, const float* __restrict__ eB1,
    const float* __restrict__ eW2, const float* __restrict__ eB2,
    ushort* __restrict__ Tp,
    const float* __restrict__ fW0, const float* __restrict__ fW1,
    const float* __restrict__ fW2,
    _Float16* __restrict__ W0T, _Float16* __restrict__ W1T,
    _Float16* __restrict__ W2T)
{
    const int bx = blockIdx.x;
    const int t  = threadIdx.x;

    if (bx >= 64) {
        const int total = 768000 + 115200 + 115200;
        for (int idx = (bx - 64) * 256 + t; idx < total; idx += 64 * 256) {
            if (idx < 768000) {
                const int tp = idx / 384000, r = idx - tp * 384000;
                const int k = r / 240, n = r - k * 240;
                W0T[tp * 384000 + n * 1600 + k] = (_Float16)fW0[idx];
            } else if (idx < 883200) {
                const int j = idx - 768000;
                const int tp = j / 57600, r = j - tp * 57600;
                const int k = r / 240, n = r - k * 240;
                W1T[tp * 57600 + n * 240 + k] = (_Float16)fW1[j];
            } else {
                const int j = idx - 883200;
                const int tp = j / 57600, r = j - tp * 57600;
                const int k = r / 240, n = r - k * 240;
                W2T[tp * 57600 + n * 240 + k] = (_Float16)fW2[j];
            }
        }
        return;
    }

    __shared__ float sm[TSMEM];
    const int w    = t >> 6;
    const int lane = t & 63;
    const int mi   = lane & 7;
    const int gi   = lane >> 3;
    const int mrow = w * 32 + mi * 4;

    const int e  = bx >> 4;
    const int k0 = (bx & 15) * 128;

    for (int idx = t; idx < 1250; idx += 256) {
        int k = idx / 50, g = idx - k * 50;
        sm[TOFF_W1 + k * 52 + g] = eW1[e * 1250 + idx];
    }
    for (int idx = t; idx < 5000; idx += 256) {
        int k = idx / 100, r = idx - k * 100;
        int half = r / 50, g = r - half * 50;
        sm[TOFF_W2 + k * 104 + half * 52 + g] = eW2[e * 5000 + idx];
    }
    if (t < 25)       { sm[TOFF_W0 + t] = eW0[e * 25 + t]; sm[TOFF_B0 + t] = eB0[e * 25 + t]; }
    else if (t < 75)  { sm[TOFF_B1 + (t - 25)] = eB1[e * 50 + (t - 25)]; }
    else if (t < 175) { sm[TOFF_B2 + (t - 75)] = eB2[e * 100 + (t - 75)]; }
    __syncthreads();

    if (t < 128) {
        const float S = TLO + (float)(k0 + t) * (1.0f / TINVH);
        #pragma unroll
        for (int k = 0; k < 25; ++k)
            sm[TOFF_H0T + k * 132 + t] = fast_tanh(S * sm[TOFF_W0 + k] + sm[TOFF_B0 + k]);
    }
    __syncthreads();

    {
        float acc[4][8];
        #pragma unroll
        for (int r = 0; r < 4; ++r)
            #pragma unroll
            for (int c = 0; c < 8; ++c) acc[r][c] = 0.f;

        #pragma unroll 5
        for (int k = 0; k < 25; ++k) {
            const float4 av = *(const float4*)&sm[TOFF_H0T + k * 132 + mrow];
            const float4 b0 = *(const float4*)&sm[TOFF_W1 + k * 52 + gi * 8];
            const float4 b1 = *(const float4*)&sm[TOFF_W1 + k * 52 + gi * 8 + 4];
            FMA_ROW(0, av.x) FMA_ROW(1, av.y) FMA_ROW(2, av.z) FMA_ROW(3, av.w)
        }
        #pragma unroll
        for (int c = 0; c < 8; ++c) {
            const int g = gi * 8 + c;
            if (g < 50) {
                const int gm = (g < 25) ? g : g - 25;
                const float4 h0r = *(const float4*)&sm[TOFF_H0T + gm * 132 + mrow];
                const float bias = sm[TOFF_B1 + g];
                float4 o;
                o.x = fast_tanh(acc[0][c] + bias) + h0r.x;
                o.y = fast_tanh(acc[1][c] + bias) + h0r.y;
                o.z = fast_tanh(acc[2][c] + bias) + h0r.z;
                o.w = fast_tanh(acc[3][c] + bias) + h0r.w;
                *(float4*)&sm[TOFF_H1T + g * 132 + mrow] = o;
            }
        }
    }
    __syncthreads();

    for (int half = 0; half < 2; ++half) {
        float acc[4][8];
        #pragma unroll
        for (int r = 0; r < 4; ++r)
            #pragma unroll
            for (int c = 0; c < 8; ++c) acc[r][c] = 0.f;

        #pragma unroll 5
        for (int k = 0; k < 50; ++k) {
            const float4 av = *(const float4*)&sm[TOFF_H1T + k * 132 + mrow];
            const float4 b0 = *(const float4*)&sm[TOFF_W2 + k * 104 + half * 52 + gi * 8];
            const float4 b1 = *(const float4*)&sm[TOFF_W2 + k * 104 + half * 52 + gi * 8 + 4];
            FMA_ROW(0, av.x) FMA_ROW(1, av.y) FMA_ROW(2, av.z) FMA_ROW(3, av.w)
        }
        #pragma unroll
        for (int c = 0; c < 8; ++c) {
            const int g = gi * 8 + c;
            if (g < 50) {
                const float4 h1r = *(const float4*)&sm[TOFF_H1T + g * 132 + mrow];
                const float bias = sm[TOFF_B2 + half * 50 + g];
                const int col = half * 50 + g;
                float vv[4];
                vv[0] = fast_tanh(acc[0][c] + bias) + h1r.x;
                vv[1] = fast_tanh(acc[1][c] + bias) + h1r.y;
                vv[2] = fast_tanh(acc[2][c] + bias) + h1r.z;
                vv[3] = fast_tanh(acc[3][c] + bias) + h1r.w;
                #pragma unroll
                for (int r = 0; r < 4; ++r) {
                    const int kk = k0 + mrow + r;
                    const _Float16 hf = (_Float16)vv[r];
                    const ushort hs = *(const ushort*)&hf;
                    const size_t base = ((size_t)e * NK + kk) * 100 + col;
                    Tp[2 * base] = hs;                       // lo of entry kk
                    if (kk > 0) Tp[2 * base - 199] = hs;     // hi of entry kk-1
                }
            }
        }
    }
}

// ---------------------------------------------------------------------------
// k_xyz: per atom gather+lerp from f16-pair table + reduce + DR(f16).
// One 4B load per (m, g) gives both lerp endpoints.
// ---------------------------------------------------------------------------
__global__ __launch_bounds__(256) void k_xyz(
    const float* __restrict__ Ri, const ushort* __restrict__ Tp,
    _Float16* __restrict__ DRh)
{
    __shared__ float4 sR[256];
    __shared__ float  sF[256];
    __shared__ int    sI[256];
    __shared__ float  sXYZ[400];

    const int t    = threadIdx.x;
    const int w    = t >> 6;
    const int lane = t & 63;
    const int blk  = blockIdx.x;         // 0..2047
    const int b    = blk >> 9;
    const int i    = (blk >> 8) & 1;
    const int n    = blk & 255;

    for (int idx = t; idx < 400; idx += 256) sXYZ[idx] = 0.f;

    {
        const int jj = t >> 7, m = t & 127;
        const size_t row = ((size_t)(b * 512 + i * 256 + n)) * 256 + jj * 128 + m;
        const float4 r = *(const float4*)(Ri + row * 4);
        sR[t] = r;
        float u = (r.x - TLO) * TINVH;
        int ii = (int)u;
        ii = (ii < 0) ? 0 : ((ii > NK - 2) ? NK - 2 : ii);
        sI[t] = ii;
        sF[t] = u - (float)ii;
    }
    __syncthreads();

    float a0[4] = {0.f, 0.f, 0.f, 0.f};
    float a1[4] = {0.f, 0.f, 0.f, 0.f};

    for (int jj = 0; jj < 2; ++jj) {
        const h2v* Te = (const h2v*)Tp + (size_t)(i * 2 + jj) * NK * 100;
        #pragma unroll 8
        for (int mm = 0; mm < 32; ++mm) {
            const int s = jj * 128 + (w << 5) + mm;
            const int row = sI[s];
            const float f = sF[s];
            const float4 R = sR[s];
            const h2v* p = Te + (size_t)row * 100;
            const h2v hv = p[lane];
            const float v0 = (float)hv[0];
            const float G = v0 + f * ((float)hv[1] - v0);
            a0[0] += R.x * G; a0[1] += R.y * G; a0[2] += R.z * G; a0[3] += R.w * G;
            if (lane < 36) {
                const h2v hu = p[64 + lane];
                const float u0 = (float)hu[0];
                const float G2 = u0 + f * ((float)hu[1] - u0);
                a1[0] += R.x * G2; a1[1] += R.y * G2; a1[2] += R.z * G2; a1[3] += R.w * G2;
            }
        }
    }

    #pragma unroll
    for (int c = 0; c < 4; ++c) atomicAdd(&sXYZ[c * 100 + lane], a0[c]);
    if (lane < 36) {
        #pragma unroll
        for (int c = 0; c < 4; ++c) atomicAdd(&sXYZ[c * 100 + 64 + lane], a1[c]);
    }
    __syncthreads();

    const float inv = 1.0f / 65536.0f;
    _Float16* dr = DRh + (((size_t)i * 4 + b) * 256 + n) * FIT_IN;
    for (int q = t; q < 400; q += 256) {
        const int gg = q >> 2, h0 = (q & 3) * 4;
        ushort4 pk;
        _Float16* ph = (_Float16*)&pk;
        #pragma unroll
        for (int r = 0; r < 4; ++r) {
            const int h = h0 + r;
            const float v = (sXYZ[gg] * sXYZ[h] + sXYZ[100 + gg] * sXYZ[100 + h]
                           + sXYZ[200 + gg] * sXYZ[200 + h] + sXYZ[300 + gg] * sXYZ[300 + h]) * inv;
            ph[r] = (_Float16)v;
        }
        *(ushort4*)(dr + gg * 16 + h0) = pk;
    }
}

// ---------------------------------------------------------------------------
// k_fit0: split-K partial GEMM for layer 0. M=32, N=240, f16 MFMA.
// grid (64 m-tiles, 8 k-slices). P[ks][2048][240] f32.
// ---------------------------------------------------------------------------
__global__ __launch_bounds__(256) void k_fit0(
    const _Float16* __restrict__ A, const _Float16* __restrict__ WT,
    float* __restrict__ P)
{
    constexpr int K = FIT_IN, CHUNK = 200;
    __shared__ _Float16 sA[32 * 40];
    __shared__ _Float16 sBT[240 * 40];

    const int t    = threadIdx.x;
    const int w    = t >> 6;
    const int lane = t & 63;
    const int ln   = lane & 15;
    const int quad = lane >> 4;

    const int mtile = blockIdx.x;        // 0..63
    const int ks    = blockIdx.y;        // 0..7
    const int row0  = mtile * 32;
    const int tp    = mtile >> 5;
    const int kbeg  = ks * CHUNK, kend = kbeg + CHUNK;
    const int nf0   = w * 4;

    f4v acc[2][4];
    #pragma unroll
    for (int mf = 0; mf < 2; ++mf)
        #pragma unroll
        for (int nf = 0; nf < 4; ++nf) acc[mf][nf] = (f4v)0.f;

    const _Float16* Ab = A + (size_t)row0 * K;
    const _Float16* Wb = WT + (size_t)tp * 240 * K;

    for (int k0 = kbeg; k0 < kend; k0 += 32) {
        {
            const int m = t >> 3, kq = (t & 7) * 4;
            const int k = k0 + kq;
            uint2 v = make_uint2(0u, 0u);
            if (k < kend) v = *(const uint2*)(Ab + (size_t)m * K + k);
            *(uint2*)&sA[m * 40 + kq] = v;
        }
        for (int q = t; q < 1920; q += 256) {
            const int nn = q >> 3, kq = (q & 7) * 4;
            const int k = k0 + kq;
            uint2 v = make_uint2(0u, 0u);
            if (k < kend) v = *(const uint2*)(Wb + (size_t)nn * K + k);
            *(uint2*)&sBT[nn * 40 + kq] = v;
        }
        __syncthreads();

        h8 afr[2];
        #pragma unroll
        for (int mf = 0; mf < 2; ++mf)
            afr[mf] = *(const h8*)&sA[(mf * 16 + ln) * 40 + quad * 8];
        #pragma unroll
        for (int nf = 0; nf < 4; ++nf) {
            const int n15 = nf0 + nf;
            if (n15 < 15) {
                const h8 bfr = *(const h8*)&sBT[(n15 * 16 + ln) * 40 + quad * 8];
                #pragma unroll
                for (int mf = 0; mf < 2; ++mf)
                    acc[mf][nf] = __builtin_amdgcn_mfma_f32_16x16x32_f16(
                        afr[mf], bfr, acc[mf][nf], 0, 0, 0);
            }
        }
        __syncthreads();
    }

    float* Pb = P + ((size_t)ks * 2048 + row0) * FH;
    #pragma unroll
    for (int nf = 0; nf < 4; ++nf) {
        const int n15 = nf0 + nf;
        if (n15 < 15) {
            const int col = n15 * 16 + ln;
            #pragma unroll
            for (int mf = 0; mf < 2; ++mf)
                #pragma unroll
                for (int r = 0; r < 4; ++r)
                    Pb[(size_t)(mf * 16 + quad * 4 + r) * FH + col] = acc[mf][nf][r];
        }
    }
}

// ---------------------------------------------------------------------------
// k_fit_tail: per 16-row block: h0=tanh(sumP+b0); h1=tanh(h0@W1+b1)+h0;
// h2=tanh(h1@W2+b2)+h1; out=h2.W3+b3. Residuals kept in LDS (in-place).
// sA16 cols 240..263 are ZERO-FILLED (k0=224 MFMA frag reads up to col 255;
// uninitialized LDS f16 can be NaN and NaN*0=NaN — the R9 bug).
// ---------------------------------------------------------------------------
__global__ __launch_bounds__(256) void k_fit_tail(
    const float* __restrict__ P, const float* __restrict__ b0,
    const _Float16* __restrict__ W1T, const float* __restrict__ b1,
    const _Float16* __restrict__ W2T, const float* __restrict__ b2,
    const float* __restrict__ W3, const float* __restrict__ b3,
    float* __restrict__ out)
{
    __shared__ float    sAf[16 * 240];   // residual (f32), reused across layers
    __shared__ _Float16 sA16[16 * 264];  // MFMA A operand (f16), k-padded
    __shared__ _Float16 sBT[240 * 40];   // streamed W chunk
    __shared__ float    sW3[240];

    const int t    = threadIdx.x;
    const int w    = t >> 6;
    const int lane = t & 63;
    const int ln   = lane & 15;
    const int quad = lane >> 4;

    const int m0 = blockIdx.x * 16;
    const int tp = m0 >> 10;
    const int nf0 = w * 4;

    // ---- stage A = tanh(sum_ks P + b0); zero-pad sA16 cols 240..263 ----
    {
        const int mr = t >> 4, c0 = t & 15;
        #pragma unroll
        for (int it = 0; it < 15; ++it) {
            const int c = c0 + it * 16;
            float s = 0.f;
            #pragma unroll
            for (int ks = 0; ks < 8; ++ks)
                s += P[(size_t)ks * 2048 * FH + (size_t)(m0 + mr) * FH + c];
            const float v = fast_tanh(s + b0[tp * FH + c]);
            sAf[mr * 240 + c] = v;
            sA16[mr * 264 + c] = (_Float16)v;
        }
        sA16[mr * 264 + 240 + c0] = (_Float16)0.f;
        if (c0 < 8) sA16[mr * 264 + 256 + c0] = (_Float16)0.f;
    }
    if (t < 240) sW3[t] = W3[tp * FH + t];
    __syncthreads();

    // ---- two residual layers ----
    for (int layer = 0; layer < 2; ++layer) {
        const _Float16* Wb = (layer == 0 ? W1T : W2T) + (size_t)tp * 240 * 240;
        const float* Bias  = (layer == 0 ? b1 : b2);

        f4v acc[4];
        #pragma unroll
        for (int nf = 0; nf < 4; ++nf) acc[nf] = (f4v)0.f;

        for (int k0 = 0; k0 < 240; k0 += 32) {
            for (int q = t; q < 1920; q += 256) {
                const int nn = q >> 3, kq = (q & 7) * 4;
                const int k = k0 + kq;
                uint2 v = make_uint2(0u, 0u);
                if (k < 240) v = *(const uint2*)(Wb + (size_t)nn * 240 + k);
                *(uint2*)&sBT[nn * 40 + kq] = v;
            }
            __syncthreads();

            const h8 afr = *(const h8*)&sA16[ln * 264 + k0 + quad * 8];
            #pragma unroll
            for (int nf = 0; nf < 4; ++nf) {
                const int n15 = nf0 + nf;
                if (n15 < 15) {
                    const h8 bfr = *(const h8*)&sBT[(n15 * 16 + ln) * 40 + quad * 8];
                    acc[nf] = __builtin_amdgcn_mfma_f32_16x16x32_f16(afr, bfr, acc[nf], 0, 0, 0);
                }
            }
            __syncthreads();
        }

        // epilogue: in-place residual update (each element owned by one thread)
        #pragma unroll
        for (int nf = 0; nf < 4; ++nf) {
            const int n15 = nf0 + nf;
            if (n15 < 15) {
                const int col = n15 * 16 + ln;
                #pragma unroll
                for (int r = 0; r < 4; ++r) {
                    const int row = quad * 4 + r;
                    const float v = fast_tanh(acc[nf][r] + Bias[tp * FH + col])
                                  + sAf[row * 240 + col];
                    sAf[row * 240 + col] = v;
                    sA16[row * 264 + col] = (_Float16)v;
                }
            }
        }
        __syncthreads();
    }

    // ---- final dot: wave w handles rows w*4 .. w*4+3 ----
    #pragma unroll
    for (int rr = 0; rr < 4; ++rr) {
        const int row = w * 4 + rr;
        float s = 0.f;
        #pragma unroll
        for (int it = 0; it < 4; ++it) {
            const int c = lane + it * 64;
            if (c < 240) s += sAf[row * 240 + c] * sW3[c];
        }
        #pragma unroll
        for (int off = 32; off > 0; off >>= 1) s += __shfl_down(s, off);
        if (lane == 0) {
            const int g = m0 + row;
            const int rem = g & 1023;
            const int bb = rem >> 8, nn = rem & 255;
            out[bb * 512 + tp * 256 + nn] = s + b3[tp];
        }
    }
}

// ---------------------------------------------------------------------------
extern "C" void kernel_launch(void* const* d_in, const int* in_sizes, int n_in,
                              void* d_out, int out_size, void* d_ws, size_t ws_size,
                              hipStream_t stream)
{
    const float* Ri  = (const float*)d_in[0];
    const float* eW0 = (const float*)d_in[1];
    const float* eB0 = (const float*)d_in[2];
    const float* eW1 = (const float*)d_in[3];
    const float* eB1 = (const float*)d_in[4];
    const float* eW2 = (const float*)d_in[5];
    const float* eB2 = (const float*)d_in[6];
    const float* fW0 = (const float*)d_in[7];
    const float* fb0 = (const float*)d_in[8];
    const float* fW1 = (const float*)d_in[9];
    const float* fb1 = (const float*)d_in[10];
    const float* fW2 = (const float*)d_in[11];
    const float* fb2 = (const float*)d_in[12];
    const float* fW3 = (const float*)d_in[13];
    const float* fb3 = (const float*)d_in[14];

    char* p = (char*)d_ws;
    float* P      = (float*)p;      p += (size_t)8 * 2048 * FH * 4;    // 15.7 MB
    ushort* Tp    = (ushort*)p;     p += (size_t)4 * NK * 100 * 4;     // 3.28 MB (f16 pairs)
    _Float16* DRh = (_Float16*)p;   p += (size_t)2048 * FIT_IN * 2;    // 6.55 MB
    _Float16* W0T = (_Float16*)p;   p += (size_t)768000 * 2;
    _Float16* W1T = (_Float16*)p;   p += (size_t)115200 * 2;
    _Float16* W2T = (_Float16*)p;   p += (size_t)115200 * 2;

    k_prep<<<dim3(128), dim3(256), 0, stream>>>(eW0, eB0, eW1, eB1, eW2, eB2, Tp,
                                                fW0, fW1, fW2, W0T, W1T, W2T);
    k_xyz<<<dim3(2048), dim3(256), 0, stream>>>(Ri, Tp, DRh);
    k_fit0<<<dim3(64, 8), dim3(256), 0, stream>>>(DRh, W0T, P);
    k_fit_tail<<<dim3(128), dim3(256), 0, stream>>>(P, fb0, W1T, fb1, W2T, fb2,
                                                    fW3, fb3, (float*)d_out);
}

// Round 11
// 198.878 us; speedup vs baseline: 1.0602x; 1.0474x over previous
//
#include <hip/hip_runtime.h>
#include <hip/hip_bf16.h>

#define FH 240
#define FIT_IN 1600
#define NK 2048            // table knots per e
#define TSTRIDE 128        // padded pair-entries per knot row (512 B)
#define TLO -16.0f
#define TINVH 64.0f        // knots per unit S (h = 1/64)

typedef _Float16 h8 __attribute__((ext_vector_type(8)));
typedef _Float16 h2v __attribute__((ext_vector_type(2)));
typedef float f4v __attribute__((ext_vector_type(4)));

__device__ __forceinline__ float fast_tanh(float x) {
    float e2 = __builtin_amdgcn_exp2f(x * 2.8853900817779268f);
    return 1.0f - 2.0f * __builtin_amdgcn_rcpf(e2 + 1.0f);
}

#define FMA_ROW(r, s) \
    acc[r][0] += (s) * b0.x; acc[r][1] += (s) * b0.y; \
    acc[r][2] += (s) * b0.z; acc[r][3] += (s) * b0.w; \
    acc[r][4] += (s) * b1.x; acc[r][5] += (s) * b1.y; \
    acc[r][6] += (s) * b1.z; acc[r][7] += (s) * b1.w;

// ---------------------------------------------------------------------------
// k_prep: blocks 0..63 build the f16-PAIR table, row stride 128 entries,
// cols 100..127 zero-filled; blocks 64..127 convert fit weights to f16.
// ---------------------------------------------------------------------------
#define TOFF_W0   0
#define TOFF_B0   28
#define TOFF_B1   56
#define TOFF_B2   108
#define TOFF_W1   208
#define TOFF_W2   1508
#define TOFF_H0T  6708
#define TOFF_H1T  10008
#define TSMEM     16608

__global__ __launch_bounds__(256) void k_prep(
    const float* __restrict__ eW0, const float* __restrict__ eB0,
    const float* __restrict__ eW1, const float* __restrict__ eB1,
    const float* __restrict__ eW2, const float* __restrict__ eB2,
    ushort* __restrict__ Tp,
    const float* __restrict__ fW0, const float* __restrict__ fW1,
    const float* __restrict__ fW2,
    _Float16* __restrict__ W0T, _Float16* __restrict__ W1T,
    _Float16* __restrict__ W2T)
{
    const int bx = blockIdx.x;
    const int t  = threadIdx.x;

    if (bx >= 64) {
        const int total = 768000 + 115200 + 115200;
        for (int idx = (bx - 64) * 256 + t; idx < total; idx += 64 * 256) {
            if (idx < 768000) {
                const int tp = idx / 384000, r = idx - tp * 384000;
                const int k = r / 240, n = r - k * 240;
                W0T[tp * 384000 + n * 1600 + k] = (_Float16)fW0[idx];
            } else if (idx < 883200) {
                const int j = idx - 768000;
                const int tp = j / 57600, r = j - tp * 57600;
                const int k = r / 240, n = r - k * 240;
                W1T[tp * 57600 + n * 240 + k] = (_Float16)fW1[j];
            } else {
                const int j = idx - 883200;
                const int tp = j / 57600, r = j - tp * 57600;
                const int k = r / 240, n = r - k * 240;
                W2T[tp * 57600 + n * 240 + k] = (_Float16)fW2[j];
            }
        }
        return;
    }

    __shared__ float sm[TSMEM];
    const int w    = t >> 6;
    const int lane = t & 63;
    const int mi   = lane & 7;
    const int gi   = lane >> 3;
    const int mrow = w * 32 + mi * 4;

    const int e  = bx >> 4;
    const int k0 = (bx & 15) * 128;

    // zero-fill pad cols 100..127 for this block's 128 knots (4B per entry)
    {
        uint* Tw = (uint*)Tp;
        for (int idx = t; idx < 128 * 28; idx += 256) {
            const int kk = idx / 28, cp = 100 + idx - (idx / 28) * 28;
            Tw[((size_t)e * NK + k0 + kk) * TSTRIDE + cp] = 0u;
        }
    }

    for (int idx = t; idx < 1250; idx += 256) {
        int k = idx / 50, g = idx - k * 50;
        sm[TOFF_W1 + k * 52 + g] = eW1[e * 1250 + idx];
    }
    for (int idx = t; idx < 5000; idx += 256) {
        int k = idx / 100, r = idx - k * 100;
        int half = r / 50, g = r - half * 50;
        sm[TOFF_W2 + k * 104 + half * 52 + g] = eW2[e * 5000 + idx];
    }
    if (t < 25)       { sm[TOFF_W0 + t] = eW0[e * 25 + t]; sm[TOFF_B0 + t] = eB0[e * 25 + t]; }
    else if (t < 75)  { sm[TOFF_B1 + (t - 25)] = eB1[e * 50 + (t - 25)]; }
    else if (t < 175) { sm[TOFF_B2 + (t - 75)] = eB2[e * 100 + (t - 75)]; }
    __syncthreads();

    if (t < 128) {
        const float S = TLO + (float)(k0 + t) * (1.0f / TINVH);
        #pragma unroll
        for (int k = 0; k < 25; ++k)
            sm[TOFF_H0T + k * 132 + t] = fast_tanh(S * sm[TOFF_W0 + k] + sm[TOFF_B0 + k]);
    }
    __syncthreads();

    {
        float acc[4][8];
        #pragma unroll
        for (int r = 0; r < 4; ++r)
            #pragma unroll
            for (int c = 0; c < 8; ++c) acc[r][c] = 0.f;

        #pragma unroll 5
        for (int k = 0; k < 25; ++k) {
            const float4 av = *(const float4*)&sm[TOFF_H0T + k * 132 + mrow];
            const float4 b0 = *(const float4*)&sm[TOFF_W1 + k * 52 + gi * 8];
            const float4 b1 = *(const float4*)&sm[TOFF_W1 + k * 52 + gi * 8 + 4];
            FMA_ROW(0, av.x) FMA_ROW(1, av.y) FMA_ROW(2, av.z) FMA_ROW(3, av.w)
        }
        #pragma unroll
        for (int c = 0; c < 8; ++c) {
            const int g = gi * 8 + c;
            if (g < 50) {
                const int gm = (g < 25) ? g : g - 25;
                const float4 h0r = *(const float4*)&sm[TOFF_H0T + gm * 132 + mrow];
                const float bias = sm[TOFF_B1 + g];
                float4 o;
                o.x = fast_tanh(acc[0][c] + bias) + h0r.x;
                o.y = fast_tanh(acc[1][c] + bias) + h0r.y;
                o.z = fast_tanh(acc[2][c] + bias) + h0r.z;
                o.w = fast_tanh(acc[3][c] + bias) + h0r.w;
                *(float4*)&sm[TOFF_H1T + g * 132 + mrow] = o;
            }
        }
    }
    __syncthreads();

    for (int half = 0; half < 2; ++half) {
        float acc[4][8];
        #pragma unroll
        for (int r = 0; r < 4; ++r)
            #pragma unroll
            for (int c = 0; c < 8; ++c) acc[r][c] = 0.f;

        #pragma unroll 5
        for (int k = 0; k < 50; ++k) {
            const float4 av = *(const float4*)&sm[TOFF_H1T + k * 132 + mrow];
            const float4 b0 = *(const float4*)&sm[TOFF_W2 + k * 104 + half * 52 + gi * 8];
            const float4 b1 = *(const float4*)&sm[TOFF_W2 + k * 104 + half * 52 + gi * 8 + 4];
            FMA_ROW(0, av.x) FMA_ROW(1, av.y) FMA_ROW(2, av.z) FMA_ROW(3, av.w)
        }
        #pragma unroll
        for (int c = 0; c < 8; ++c) {
            const int g = gi * 8 + c;
            if (g < 50) {
                const float4 h1r = *(const float4*)&sm[TOFF_H1T + g * 132 + mrow];
                const float bias = sm[TOFF_B2 + half * 50 + g];
                const int col = half * 50 + g;
                float vv[4];
                vv[0] = fast_tanh(acc[0][c] + bias) + h1r.x;
                vv[1] = fast_tanh(acc[1][c] + bias) + h1r.y;
                vv[2] = fast_tanh(acc[2][c] + bias) + h1r.z;
                vv[3] = fast_tanh(acc[3][c] + bias) + h1r.w;
                #pragma unroll
                for (int r = 0; r < 4; ++r) {
                    const int kk = k0 + mrow + r;
                    const _Float16 hf = (_Float16)vv[r];
                    const ushort hs = *(const ushort*)&hf;
                    const size_t base = ((size_t)e * NK + kk) * TSTRIDE + col;
                    Tp[2 * base] = hs;                          // lo of entry kk
                    if (kk > 0) Tp[2 * (base - TSTRIDE) + 1] = hs;  // hi of entry kk-1
                }
            }
        }
    }
}

// ---------------------------------------------------------------------------
// k_xyz: per atom gather+lerp from padded f16-pair table + reduce + DR(f16).
// 8-deep manual pipeline: 16 unconditional loads in flight per wave.
// ---------------------------------------------------------------------------
__global__ __launch_bounds__(256) void k_xyz(
    const float* __restrict__ Ri, const ushort* __restrict__ Tp,
    _Float16* __restrict__ DRh)
{
    __shared__ float4 sR[256];
    __shared__ float  sF[256];
    __shared__ int    sI[256];
    __shared__ float  sXYZ[400];

    const int t    = threadIdx.x;
    const int w    = t >> 6;
    const int lane = t & 63;
    const int blk  = blockIdx.x;         // 0..2047
    const int b    = blk >> 9;
    const int i    = (blk >> 8) & 1;
    const int n    = blk & 255;

    for (int idx = t; idx < 400; idx += 256) sXYZ[idx] = 0.f;

    {
        const int jj = t >> 7, m = t & 127;
        const size_t row = ((size_t)(b * 512 + i * 256 + n)) * 256 + jj * 128 + m;
        const float4 r = *(const float4*)(Ri + row * 4);
        sR[t] = r;
        float u = (r.x - TLO) * TINVH;
        int ii = (int)u;
        ii = (ii < 0) ? 0 : ((ii > NK - 2) ? NK - 2 : ii);
        sI[t] = ii;
        sF[t] = u - (float)ii;
    }
    __syncthreads();

    float a0[4] = {0.f, 0.f, 0.f, 0.f};
    float a1[4] = {0.f, 0.f, 0.f, 0.f};

    for (int jj = 0; jj < 2; ++jj) {
        const h2v* Te = (const h2v*)Tp + (size_t)(i * 2 + jj) * NK * TSTRIDE;
        for (int m8 = 0; m8 < 32; m8 += 8) {
            h2v va[8], vb[8];
            #pragma unroll
            for (int k = 0; k < 8; ++k) {
                const int s = jj * 128 + (w << 5) + m8 + k;
                const h2v* p = Te + (size_t)sI[s] * TSTRIDE;
                va[k] = p[lane];
                vb[k] = p[64 + lane];
            }
            #pragma unroll
            for (int k = 0; k < 8; ++k) {
                const int s = jj * 128 + (w << 5) + m8 + k;
                const float f = sF[s];
                const float4 R = sR[s];
                const float v0 = (float)va[k][0];
                const float G = v0 + f * ((float)va[k][1] - v0);
                a0[0] += R.x * G; a0[1] += R.y * G; a0[2] += R.z * G; a0[3] += R.w * G;
                const float u0 = (float)vb[k][0];
                const float G2 = u0 + f * ((float)vb[k][1] - u0);   // pad cols -> 0
                a1[0] += R.x * G2; a1[1] += R.y * G2; a1[2] += R.z * G2; a1[3] += R.w * G2;
            }
        }
    }

    #pragma unroll
    for (int c = 0; c < 4; ++c) atomicAdd(&sXYZ[c * 100 + lane], a0[c]);
    if (lane < 36) {
        #pragma unroll
        for (int c = 0; c < 4; ++c) atomicAdd(&sXYZ[c * 100 + 64 + lane], a1[c]);
    }
    __syncthreads();

    const float inv = 1.0f / 65536.0f;
    _Float16* dr = DRh + (((size_t)i * 4 + b) * 256 + n) * FIT_IN;
    for (int q = t; q < 400; q += 256) {
        const int gg = q >> 2, h0 = (q & 3) * 4;
        ushort4 pk;
        _Float16* ph = (_Float16*)&pk;
        #pragma unroll
        for (int r = 0; r < 4; ++r) {
            const int h = h0 + r;
            const float v = (sXYZ[gg] * sXYZ[h] + sXYZ[100 + gg] * sXYZ[100 + h]
                           + sXYZ[200 + gg] * sXYZ[200 + h] + sXYZ[300 + gg] * sXYZ[300 + h]) * inv;
            ph[r] = (_Float16)v;
        }
        *(ushort4*)(dr + gg * 16 + h0) = pk;
    }
}

// ---------------------------------------------------------------------------
// k_fit0: split-K partial GEMM for layer 0. M=32, N=240, f16 MFMA.
// grid (64 m-tiles, 8 k-slices). P[ks][2048][240] f32.
// ---------------------------------------------------------------------------
__global__ __launch_bounds__(256) void k_fit0(
    const _Float16* __restrict__ A, const _Float16* __restrict__ WT,
    float* __restrict__ P)
{
    constexpr int K = FIT_IN, CHUNK = 200;
    __shared__ _Float16 sA[32 * 40];
    __shared__ _Float16 sBT[240 * 40];

    const int t    = threadIdx.x;
    const int w    = t >> 6;
    const int lane = t & 63;
    const int ln   = lane & 15;
    const int quad = lane >> 4;

    const int mtile = blockIdx.x;        // 0..63
    const int ks    = blockIdx.y;        // 0..7
    const int row0  = mtile * 32;
    const int tp    = mtile >> 5;
    const int kbeg  = ks * CHUNK, kend = kbeg + CHUNK;
    const int nf0   = w * 4;

    f4v acc[2][4];
    #pragma unroll
    for (int mf = 0; mf < 2; ++mf)
        #pragma unroll
        for (int nf = 0; nf < 4; ++nf) acc[mf][nf] = (f4v)0.f;

    const _Float16* Ab = A + (size_t)row0 * K;
    const _Float16* Wb = WT + (size_t)tp * 240 * K;

    for (int k0 = kbeg; k0 < kend; k0 += 32) {
        {
            const int m = t >> 3, kq = (t & 7) * 4;
            const int k = k0 + kq;
            uint2 v = make_uint2(0u, 0u);
            if (k < kend) v = *(const uint2*)(Ab + (size_t)m * K + k);
            *(uint2*)&sA[m * 40 + kq] = v;
        }
        for (int q = t; q < 1920; q += 256) {
            const int nn = q >> 3, kq = (q & 7) * 4;
            const int k = k0 + kq;
            uint2 v = make_uint2(0u, 0u);
            if (k < kend) v = *(const uint2*)(Wb + (size_t)nn * K + k);
            *(uint2*)&sBT[nn * 40 + kq] = v;
        }
        __syncthreads();

        h8 afr[2];
        #pragma unroll
        for (int mf = 0; mf < 2; ++mf)
            afr[mf] = *(const h8*)&sA[(mf * 16 + ln) * 40 + quad * 8];
        #pragma unroll
        for (int nf = 0; nf < 4; ++nf) {
            const int n15 = nf0 + nf;
            if (n15 < 15) {
                const h8 bfr = *(const h8*)&sBT[(n15 * 16 + ln) * 40 + quad * 8];
                #pragma unroll
                for (int mf = 0; mf < 2; ++mf)
                    acc[mf][nf] = __builtin_amdgcn_mfma_f32_16x16x32_f16(
                        afr[mf], bfr, acc[mf][nf], 0, 0, 0);
            }
        }
        __syncthreads();
    }

    float* Pb = P + ((size_t)ks * 2048 + row0) * FH;
    #pragma unroll
    for (int nf = 0; nf < 4; ++nf) {
        const int n15 = nf0 + nf;
        if (n15 < 15) {
            const int col = n15 * 16 + ln;
            #pragma unroll
            for (int mf = 0; mf < 2; ++mf)
                #pragma unroll
                for (int r = 0; r < 4; ++r)
                    Pb[(size_t)(mf * 16 + quad * 4 + r) * FH + col] = acc[mf][nf][r];
        }
    }
}

// ---------------------------------------------------------------------------
// k_fit_tail: per 16-row block: h0=tanh(sumP+b0); h1=tanh(h0@W1+b1)+h0;
// h2=tanh(h1@W2+b2)+h1; out=h2.W3+b3. Residuals in LDS; sA16 k-pad zeroed.
// ---------------------------------------------------------------------------
__global__ __launch_bounds__(256) void k_fit_tail(
    const float* __restrict__ P, const float* __restrict__ b0,
    const _Float16* __restrict__ W1T, const float* __restrict__ b1,
    const _Float16* __restrict__ W2T, const float* __restrict__ b2,
    const float* __restrict__ W3, const float* __restrict__ b3,
    float* __restrict__ out)
{
    __shared__ float    sAf[16 * 240];
    __shared__ _Float16 sA16[16 * 264];
    __shared__ _Float16 sBT[240 * 40];
    __shared__ float    sW3[240];

    const int t    = threadIdx.x;
    const int w    = t >> 6;
    const int lane = t & 63;
    const int ln   = lane & 15;
    const int quad = lane >> 4;

    const int m0 = blockIdx.x * 16;
    const int tp = m0 >> 10;
    const int nf0 = w * 4;

    {
        const int mr = t >> 4, c0 = t & 15;
        #pragma unroll
        for (int it = 0; it < 15; ++it) {
            const int c = c0 + it * 16;
            float s = 0.f;
            #pragma unroll
            for (int ks = 0; ks < 8; ++ks)
                s += P[(size_t)ks * 2048 * FH + (size_t)(m0 + mr) * FH + c];
            const float v = fast_tanh(s + b0[tp * FH + c]);
            sAf[mr * 240 + c] = v;
            sA16[mr * 264 + c] = (_Float16)v;
        }
        sA16[mr * 264 + 240 + c0] = (_Float16)0.f;
        if (c0 < 8) sA16[mr * 264 + 256 + c0] = (_Float16)0.f;
    }
    if (t < 240) sW3[t] = W3[tp * FH + t];
    __syncthreads();

    for (int layer = 0; layer < 2; ++layer) {
        const _Float16* Wb = (layer == 0 ? W1T : W2T) + (size_t)tp * 240 * 240;
        const float* Bias  = (layer == 0 ? b1 : b2);

        f4v acc[4];
        #pragma unroll
        for (int nf = 0; nf < 4; ++nf) acc[nf] = (f4v)0.f;

        for (int k0 = 0; k0 < 240; k0 += 32) {
            for (int q = t; q < 1920; q += 256) {
                const int nn = q >> 3, kq = (q & 7) * 4;
                const int k = k0 + kq;
                uint2 v = make_uint2(0u, 0u);
                if (k < 240) v = *(const uint2*)(Wb + (size_t)nn * 240 + k);
                *(uint2*)&sBT[nn * 40 + kq] = v;
            }
            __syncthreads();

            const h8 afr = *(const h8*)&sA16[ln * 264 + k0 + quad * 8];
            #pragma unroll
            for (int nf = 0; nf < 4; ++nf) {
                const int n15 = nf0 + nf;
                if (n15 < 15) {
                    const h8 bfr = *(const h8*)&sBT[(n15 * 16 + ln) * 40 + quad * 8];
                    acc[nf] = __builtin_amdgcn_mfma_f32_16x16x32_f16(afr, bfr, acc[nf], 0, 0, 0);
                }
            }
            __syncthreads();
        }

        #pragma unroll
        for (int nf = 0; nf < 4; ++nf) {
            const int n15 = nf0 + nf;
            if (n15 < 15) {
                const int col = n15 * 16 + ln;
                #pragma unroll
                for (int r = 0; r < 4; ++r) {
                    const int row = quad * 4 + r;
                    const float v = fast_tanh(acc[nf][r] + Bias[tp * FH + col])
                                  + sAf[row * 240 + col];
                    sAf[row * 240 + col] = v;
                    sA16[row * 264 + col] = (_Float16)v;
                }
            }
        }
        __syncthreads();
    }

    #pragma unroll
    for (int rr = 0; rr < 4; ++rr) {
        const int row = w * 4 + rr;
        float s = 0.f;
        #pragma unroll
        for (int it = 0; it < 4; ++it) {
            const int c = lane + it * 64;
            if (c < 240) s += sAf[row * 240 + c] * sW3[c];
        }
        #pragma unroll
        for (int off = 32; off > 0; off >>= 1) s += __shfl_down(s, off);
        if (lane == 0) {
            const int g = m0 + row;
            const int rem = g & 1023;
            const int bb = rem >> 8, nn = rem & 255;
            out[bb * 512 + tp * 256 + nn] = s + b3[tp];
        }
    }
}

// ---------------------------------------------------------------------------
extern "C" void kernel_launch(void* const* d_in, const int* in_sizes, int n_in,
                              void* d_out, int out_size, void* d_ws, size_t ws_size,
                              hipStream_t stream)
{
    const float* Ri  = (const float*)d_in[0];
    const float* eW0 = (const float*)d_in[1];
    const float* eB0 = (const float*)d_in[2];
    const float* eW1 = (const float*)d_in[3];
    const float* eB1 = (const float*)d_in[4];
    const float* eW2 = (const float*)d_in[5];
    const float* eB2 = (const float*)d_in[6];
    const float* fW0 = (const float*)d_in[7];
    const float* fb0 = (const float*)d_in[8];
    const float* fW1 = (const float*)d_in[9];
    const float* fb1 = (const float*)d_in[10];
    const float* fW2 = (const float*)d_in[11];
    const float* fb2 = (const float*)d_in[12];
    const float* fW3 = (const float*)d_in[13];
    const float* fb3 = (const float*)d_in[14];

    char* p = (char*)d_ws;
    float* P      = (float*)p;      p += (size_t)8 * 2048 * FH * 4;        // 15.7 MB
    ushort* Tp    = (ushort*)p;     p += (size_t)4 * NK * TSTRIDE * 4;     // 4.19 MB
    _Float16* DRh = (_Float16*)p;   p += (size_t)2048 * FIT_IN * 2;        // 6.55 MB
    _Float16* W0T = (_Float16*)p;   p += (size_t)768000 * 2;
    _Float16* W1T = (_Float16*)p;   p += (size_t)115200 * 2;
    _Float16* W2T = (_Float16*)p;   p += (size_t)115200 * 2;

    k_prep<<<dim3(128), dim3(256), 0, stream>>>(eW0, eB0, eW1, eB1, eW2, eB2, Tp,
                                                fW0, fW1, fW2, W0T, W1T, W2T);
    k_xyz<<<dim3(2048), dim3(256), 0, stream>>>(Ri, Tp, DRh);
    k_fit0<<<dim3(64, 8), dim3(256), 0, stream>>>(DRh, W0T, P);
    k_fit_tail<<<dim3(128), dim3(256), 0, stream>>>(P, fb0, W1T, fb1, W2T, fb2,
                                                    fW3, fb3, (float*)d_out);
}